// Round 7
// baseline (342.556 us; speedup 1.0000x reference)
//
#include <hip/hip_runtime.h>

#define N_IMG 4
#define E_DIM 16
#define P_PIX 320000
#define C_CLS 20
#define CK 19                 // classes 1..19 (IGNORE = 0 excluded)
#define MSTRIDE 17            // mean-tile stride: 17 invertible mod 32
#define CSTR 3                // class stride in accumulator LDS: 3 invertible mod 32
#define TILE 256              // pixels per block

// ws layout (floats): sums[n][c][e], counts[n][c], means[n][c][e], loss
#define SUMS_OFF 0
#define CNT_OFF  (N_IMG * C_CLS * E_DIM)            // 1280
#define MEAN_OFF (CNT_OFF + N_IMG * C_CLS)          // 1360
#define LOSS_OFF (MEAN_OFF + N_IMG * C_CLS * E_DIM) // 2640
#define WS_FLOATS (LOSS_OFF + 1)

// Async global->LDS DMA (no dest VGPRs => MLP guaranteed by the hardware queue;
// rounds 2/4/5/6 proved the compiler will not keep 16 load results live).
// LDS dest semantics: wave-uniform base, lane i writes [base + i*16B, +16B).
typedef __attribute__((address_space(1))) const void gvoid_t;
typedef __attribute__((address_space(3))) void svoid_t;
__device__ __forceinline__ void async16(const void* g, void* l) {
    __builtin_amdgcn_global_load_lds((gvoid_t*)g, (svoid_t*)l, 16, 0, 0);
}

// ---------------- Kernel 1: per-class sums + counts ----------------
// Stage 256 pixels x 16 channels (16 KB) + 256 labels via global_load_lds
// (17 x 1KB async instrs per block), then all-LDS consumption.
__global__ __launch_bounds__(256) void k_sums(const float* __restrict__ emb,
                                              const int* __restrict__ target,
                                              float* __restrict__ ws) {
    __shared__ float tile[E_DIM * TILE];   // [e][pix], 16 KB
    __shared__ int   ltgt[TILE];           // 1 KB
    __shared__ float lsum[E_DIM * 64];     // [e][c*3+rep], 4 KB
    __shared__ float lcnt[64];
    const int tid = threadIdx.x, n = blockIdx.y;
    const int wave = tid >> 6, lane = tid & 63;
    const int pix0 = blockIdx.x * TILE;
    const int rep = tid & 1;

    const float* embn = emb + (size_t)n * E_DIM * P_PIX;
    // wave w stages channels 4w..4w+3: one 1KB async DMA per channel row
#pragma unroll
    for (int j = 0; j < 4; j++) {
        const int c = wave * 4 + j;
        async16(embn + (size_t)c * P_PIX + pix0 + lane * 4, &tile[c * TILE]);
    }
    if (wave == 0)
        async16(target + (size_t)n * P_PIX + pix0 + lane * 4, ltgt);

    for (int i = tid; i < E_DIM * 64; i += 256) lsum[i] = 0.f;
    if (tid < 64) lcnt[tid] = 0.f;
    __syncthreads();   // drains vmcnt(0): all async DMAs landed

    const int lab = ltgt[tid];
    const int a = lab * CSTR + rep;        // 20 classes -> 20 distinct banks, 2 reps
    atomicAdd(&lcnt[a], 1.f);
#pragma unroll
    for (int e = 0; e < E_DIM; e++)
        atomicAdd(&lsum[e * 64 + a], tile[e * TILE + tid]);
    __syncthreads();

    for (int i = tid; i < C_CLS * E_DIM; i += 256) {
        const int c = i >> 4, e = i & 15;
        atomicAdd(ws + SUMS_OFF + (size_t)(n * C_CLS + c) * E_DIM + e,
                  lsum[e * 64 + c * CSTR] + lsum[e * 64 + c * CSTR + 1]);
    }
    if (tid < C_CLS)
        atomicAdd(ws + CNT_OFF + n * C_CLS + tid, lcnt[tid * CSTR] + lcnt[tid * CSTR + 1]);
}

// -------- Kernel 2: means + distance(push) term + regularizer --------
__global__ void k_means_dist(float* __restrict__ ws) {
    __shared__ float lmean[C_CLS * E_DIM];
    __shared__ float red[256];
    const int n = blockIdx.x, tid = threadIdx.x;

    const float* gsum = ws + SUMS_OFF + n * C_CLS * E_DIM;
    const float* gcnt = ws + CNT_OFF + n * C_CLS;
    float* gmean = ws + MEAN_OFF + n * C_CLS * E_DIM;

    for (int i = tid; i < C_CLS * E_DIM; i += blockDim.x) {
        const int c = i / E_DIM;
        const float cnt = gcnt[c];
        const float m = (cnt > 0.f) ? gsum[i] / cnt : 0.f;
        lmean[i] = m;
        gmean[i] = m;
    }
    __syncthreads();

    float acc = 0.f;
    for (int idx = tid; idx < CK * CK; idx += blockDim.x) {
        const int i = idx / CK + 1, j = idx % CK + 1;
        if (i != j) {
            float sq = 0.f;
#pragma unroll
            for (int e = 0; e < E_DIM; e++) {
                const float d = lmean[i * E_DIM + e] - lmean[j * E_DIM + e];
                sq += d * d;
            }
            const float dm = sqrtf(sq);
            const float h = fmaxf(3.0f - dm, 0.f);   // 2*DELTA_DIST = 3
            acc += h * h;
        }
    }
    acc *= 1.0f / (float)(CK * (CK - 1));            // BETA = 1

    float racc = 0.f;
    for (int c = tid + 1; c < C_CLS; c += blockDim.x) {
        float sq = 0.f;
#pragma unroll
        for (int e = 0; e < E_DIM; e++) {
            const float m = lmean[c * E_DIM + e];
            sq += m * m;
        }
        racc += sqrtf(sq);
    }
    acc += 0.001f * racc / (float)CK;                // GAMMA = 0.001

    red[tid] = acc;
    __syncthreads();
    for (int s = blockDim.x / 2; s > 0; s >>= 1) {
        if (tid < s) red[tid] += red[tid + s];
        __syncthreads();
    }
    if (tid == 0) atomicAdd(ws + LOSS_OFF, red[0]);
}

// ---------------- Kernel 3: variance (pull) term ----------------
// Same async-DMA staging; per-thread norm from LDS; shuffle reduction.
__global__ __launch_bounds__(256) void k_var(const float* __restrict__ emb,
                                             const int* __restrict__ target,
                                             float* __restrict__ ws) {
    __shared__ float tile[E_DIM * TILE];   // 16 KB
    __shared__ int   ltgt[TILE];
    __shared__ float lmean[C_CLS * MSTRIDE];
    __shared__ float lw[C_CLS];
    __shared__ float wred[4];
    const int tid = threadIdx.x, n = blockIdx.y;
    const int wave = tid >> 6, lane = tid & 63;
    const int pix0 = blockIdx.x * TILE;

    const float* embn = emb + (size_t)n * E_DIM * P_PIX;
#pragma unroll
    for (int j = 0; j < 4; j++) {
        const int c = wave * 4 + j;
        async16(embn + (size_t)c * P_PIX + pix0 + lane * 4, &tile[c * TILE]);
    }
    if (wave == 0)
        async16(target + (size_t)n * P_PIX + pix0 + lane * 4, ltgt);

    const float* gmean = ws + MEAN_OFF + n * C_CLS * E_DIM;
    const float* gcnt  = ws + CNT_OFF + n * C_CLS;
    for (int i = tid; i < C_CLS * E_DIM; i += 256) {
        const int c = i >> 4, e = i & 15;
        lmean[c * MSTRIDE + e] = gmean[i];
    }
    if (tid < C_CLS) {
        const float cnt = gcnt[tid];
        lw[tid] = (tid != 0 && cnt > 0.f) ? 1.0f / (cnt * (float)CK) : 0.f;
    }
    __syncthreads();   // drains async DMAs + mean staging

    const int lab = ltgt[tid];
    const int mb = lab * MSTRIDE;
    float sq = 0.f;
#pragma unroll
    for (int e = 0; e < E_DIM; e++) {
        const float d = tile[e * TILE + tid] - lmean[mb + e];
        sq += d * d;
    }
    const float h = fmaxf(sqrtf(sq) - 0.5f, 0.f);   // DELTA_VAR = 0.5
    float acc = h * h * lw[lab];                    // lw[0]=0 masks IGNORE

#pragma unroll
    for (int off = 32; off > 0; off >>= 1) acc += __shfl_down(acc, off, 64);
    if ((tid & 63) == 0) wred[wave] = acc;
    __syncthreads();
    if (tid == 0) atomicAdd(ws + LOSS_OFF, wred[0] + wred[1] + wred[2] + wred[3]);
}

// ---------------- Kernel 4: finalize ----------------
__global__ void k_fin(const float* __restrict__ ws, float* __restrict__ out) {
    out[0] = ws[LOSS_OFF] * 0.25f;  // mean over 4 images
}

extern "C" void kernel_launch(void* const* d_in, const int* in_sizes, int n_in,
                              void* d_out, int out_size, void* d_ws, size_t ws_size,
                              hipStream_t stream) {
    const float* emb = (const float*)d_in[0];
    const int* target = (const int*)d_in[1];
    float* out = (float*)d_out;
    float* ws = (float*)d_ws;

    hipMemsetAsync(d_ws, 0, WS_FLOATS * sizeof(float), stream);

    dim3 gp(P_PIX / TILE, N_IMG);   // 1250 x 4 blocks
    k_sums<<<gp, 256, 0, stream>>>(emb, target, ws);
    k_means_dist<<<N_IMG, 256, 0, stream>>>(ws);
    k_var<<<gp, 256, 0, stream>>>(emb, target, ws);
    k_fin<<<1, 1, 0, stream>>>(ws, out);
}

// Round 8
// 245.887 us; speedup vs baseline: 1.3931x; 1.3931x over previous
//
#include <hip/hip_runtime.h>

#define N_IMG 4
#define E_DIM 16
#define P_PIX 320000
#define G_PIX (P_PIX / 4)     // 80000 float4 groups per image
#define C_CLS 20
#define CK 19                 // classes 1..19 (IGNORE = 0 = trash bin)
#define MSTRIDE 17            // mean LDS stride, invertible mod 32
#define CSTR 3                // class stride in LDS accumulators
#define SLABS 64              // replicated global accumulator tables
#define NCHUNK 313            // ceil(G_PIX / 256)

// ws layout (floats):
#define PSUM_OFF 0                                   // [s][n][e][c] 64*4*16*20 = 81920
#define PCNT_OFF 81920                               // [s][n][c]    64*4*20    = 5120
#define MEAN_OFF 87040                               // [n][c][e]                1280
#define CNTR_OFF 88320                               // [n][c]                   80
#define LOSS_OFF 88400                               // [4]
#define WS_FLOATS 88464

// ---------------- Pass 1: per-class sums + counts ----------------
// Thread owns 4 pixels (one float4 column) across ALL 16 channels: 16-iter
// rotated loop (load e+1 while consuming e), labels in registers, consumers =
// 4 LDS atomics/pass. Flush: slab-spread global atomics (64 replicas).
__global__ __launch_bounds__(256) void k_sums(const float* __restrict__ emb,
                                              const int* __restrict__ target,
                                              float* __restrict__ ws) {
    __shared__ float lsum[E_DIM * 64];   // [e][c*3+rep], 4 KB
    __shared__ float lcnt[64];
    const int tid = threadIdx.x, n = blockIdx.y;
    const int rep = tid & 1;

    for (int i = tid; i < E_DIM * 64; i += 256) lsum[i] = 0.f;
    if (tid < 64) lcnt[tid] = 0.f;
    __syncthreads();

    const int gq = blockIdx.x * 256 + tid;
    const int g = min(gq, G_PIX - 1);          // clamp; OOB labels forced to 0
    const bool valid = gq < G_PIX;
    const int4 lb = ((const int4*)target)[(size_t)n * G_PIX + g];
    const int ax = (valid ? lb.x : 0) * CSTR + rep;
    const int ay = (valid ? lb.y : 0) * CSTR + rep;
    const int az = (valid ? lb.z : 0) * CSTR + rep;
    const int aw = (valid ? lb.w : 0) * CSTR + rep;

    const float4* base = (const float4*)emb + (size_t)n * E_DIM * G_PIX + g;
    float4 v = base[0];
#pragma unroll
    for (int e = 0; e < E_DIM - 1; e++) {
        const float4 vn = base[(size_t)(e + 1) * G_PIX];   // rotation: next in flight
        atomicAdd(&lsum[e * 64 + ax], v.x);
        atomicAdd(&lsum[e * 64 + ay], v.y);
        atomicAdd(&lsum[e * 64 + az], v.z);
        atomicAdd(&lsum[e * 64 + aw], v.w);
        if (e == 0) {
            atomicAdd(&lcnt[ax], 1.f);
            atomicAdd(&lcnt[ay], 1.f);
            atomicAdd(&lcnt[az], 1.f);
            atomicAdd(&lcnt[aw], 1.f);
        }
        v = vn;
    }
    atomicAdd(&lsum[15 * 64 + ax], v.x);
    atomicAdd(&lsum[15 * 64 + ay], v.y);
    atomicAdd(&lsum[15 * 64 + az], v.z);
    atomicAdd(&lsum[15 * 64 + aw], v.w);
    __syncthreads();

    const int slab = blockIdx.x & (SLABS - 1);
    for (int i = tid; i < E_DIM * C_CLS; i += 256) {
        const int e = i / C_CLS, c = i % C_CLS;
        atomicAdd(ws + PSUM_OFF + (size_t)((slab * N_IMG + n) * E_DIM + e) * C_CLS + c,
                  lsum[e * 64 + c * CSTR] + lsum[e * 64 + c * CSTR + 1]);
    }
    if (tid < C_CLS)
        atomicAdd(ws + PCNT_OFF + (size_t)(slab * N_IMG + n) * C_CLS + tid,
                  lcnt[tid * CSTR] + lcnt[tid * CSTR + 1]);
}

// -------- Pass 2a: reduce slabs -> means/counts; push + reg terms --------
__global__ void k_means_dist(float* __restrict__ ws) {
    __shared__ float lmean[C_CLS * E_DIM];   // [c][e]
    __shared__ float lcnt2[C_CLS];
    __shared__ float red[256];
    const int n = blockIdx.x, tid = threadIdx.x;

    if (tid < C_CLS) {
        float cs = 0.f;
        for (int s = 0; s < SLABS; s++)
            cs += ws[PCNT_OFF + (size_t)(s * N_IMG + n) * C_CLS + tid];
        lcnt2[tid] = cs;
        ws[CNTR_OFF + n * C_CLS + tid] = cs;
    }
    __syncthreads();
    for (int i = tid; i < E_DIM * C_CLS; i += 256) {
        const int e = i / C_CLS, c = i % C_CLS;
        float sum = 0.f;
        const size_t base = PSUM_OFF + (size_t)(n * E_DIM + e) * C_CLS + c;
        for (int s = 0; s < SLABS; s++)
            sum += ws[base + (size_t)s * N_IMG * E_DIM * C_CLS];
        const float cnt = lcnt2[c];
        const float m = (cnt > 0.f) ? sum / cnt : 0.f;
        lmean[c * E_DIM + e] = m;
        ws[MEAN_OFF + (n * C_CLS + c) * E_DIM + e] = m;
    }
    __syncthreads();

    float acc = 0.f;
    for (int idx = tid; idx < CK * CK; idx += 256) {
        const int i = idx / CK + 1, j = idx % CK + 1;
        if (i != j) {
            float sq = 0.f;
#pragma unroll
            for (int e = 0; e < E_DIM; e++) {
                const float d = lmean[i * E_DIM + e] - lmean[j * E_DIM + e];
                sq += d * d;
            }
            const float h = fmaxf(3.0f - sqrtf(sq), 0.f);   // 2*DELTA_DIST
            acc += h * h;
        }
    }
    acc *= 1.0f / (float)(CK * (CK - 1));                    // BETA = 1

    float racc = 0.f;
    for (int c = tid + 1; c < C_CLS; c += 256) {
        float sq = 0.f;
#pragma unroll
        for (int e = 0; e < E_DIM; e++) {
            const float m = lmean[c * E_DIM + e];
            sq += m * m;
        }
        racc += sqrtf(sq);
    }
    acc += 0.001f * racc / (float)CK;                        // GAMMA

    red[tid] = acc;
    __syncthreads();
    for (int s = 128; s > 0; s >>= 1) {
        if (tid < s) red[tid] += red[tid + s];
        __syncthreads();
    }
    if (tid == 0) atomicAdd(ws + LOSS_OFF + n, red[0]);
}

// ---------------- Pass 3: variance (pull) term ----------------
// Same rotated channel loop; per-pixel squared distance lives in 4 registers.
__global__ __launch_bounds__(256) void k_var(const float* __restrict__ emb,
                                             const int* __restrict__ target,
                                             float* __restrict__ ws) {
    __shared__ float lmean[C_CLS * MSTRIDE];
    __shared__ float lw[C_CLS];
    __shared__ float wred[4];
    const int tid = threadIdx.x, n = blockIdx.y;

    for (int i = tid; i < C_CLS * E_DIM; i += 256) {
        const int c = i >> 4, e = i & 15;
        lmean[c * MSTRIDE + e] = ws[MEAN_OFF + (n * C_CLS + c) * E_DIM + e];
    }
    if (tid < C_CLS) {
        const float cnt = ws[CNTR_OFF + n * C_CLS + tid];
        lw[tid] = (tid != 0 && cnt > 0.f) ? 1.0f / (cnt * (float)CK) : 0.f;
    }
    __syncthreads();

    const int gq = blockIdx.x * 256 + tid;
    const int g = min(gq, G_PIX - 1);
    const bool valid = gq < G_PIX;
    const int4 lb = ((const int4*)target)[(size_t)n * G_PIX + g];
    const int bx = (valid ? lb.x : 0), by = (valid ? lb.y : 0);
    const int bz = (valid ? lb.z : 0), bw = (valid ? lb.w : 0);
    const int mx = bx * MSTRIDE, my = by * MSTRIDE;
    const int mz = bz * MSTRIDE, mw = bw * MSTRIDE;

    const float4* base = (const float4*)emb + (size_t)n * E_DIM * G_PIX + g;
    float4 v = base[0];
    float s0 = 0.f, s1 = 0.f, s2 = 0.f, s3 = 0.f;
#pragma unroll
    for (int e = 0; e < E_DIM - 1; e++) {
        const float4 vn = base[(size_t)(e + 1) * G_PIX];
        float d;
        d = v.x - lmean[mx + e]; s0 = fmaf(d, d, s0);
        d = v.y - lmean[my + e]; s1 = fmaf(d, d, s1);
        d = v.z - lmean[mz + e]; s2 = fmaf(d, d, s2);
        d = v.w - lmean[mw + e]; s3 = fmaf(d, d, s3);
        v = vn;
    }
    {
        float d;
        d = v.x - lmean[mx + 15]; s0 = fmaf(d, d, s0);
        d = v.y - lmean[my + 15]; s1 = fmaf(d, d, s1);
        d = v.z - lmean[mz + 15]; s2 = fmaf(d, d, s2);
        d = v.w - lmean[mw + 15]; s3 = fmaf(d, d, s3);
    }
    float h, acc = 0.f;
    h = fmaxf(sqrtf(s0) - 0.5f, 0.f); acc += h * h * lw[bx];   // DELTA_VAR = 0.5
    h = fmaxf(sqrtf(s1) - 0.5f, 0.f); acc += h * h * lw[by];   // lw[0]=0 masks
    h = fmaxf(sqrtf(s2) - 0.5f, 0.f); acc += h * h * lw[bz];
    h = fmaxf(sqrtf(s3) - 0.5f, 0.f); acc += h * h * lw[bw];

#pragma unroll
    for (int off = 32; off > 0; off >>= 1) acc += __shfl_down(acc, off, 64);
    if ((tid & 63) == 0) wred[tid >> 6] = acc;
    __syncthreads();
    if (tid == 0)
        atomicAdd(ws + LOSS_OFF + n, wred[0] + wred[1] + wred[2] + wred[3]);
}

// ---------------- finalize ----------------
__global__ void k_fin(const float* __restrict__ ws, float* __restrict__ out) {
    out[0] = (ws[LOSS_OFF] + ws[LOSS_OFF + 1] + ws[LOSS_OFF + 2] + ws[LOSS_OFF + 3]) * 0.25f;
}

extern "C" void kernel_launch(void* const* d_in, const int* in_sizes, int n_in,
                              void* d_out, int out_size, void* d_ws, size_t ws_size,
                              hipStream_t stream) {
    const float* emb = (const float*)d_in[0];
    const int* target = (const int*)d_in[1];
    float* out = (float*)d_out;
    float* ws = (float*)d_ws;

    hipMemsetAsync(d_ws, 0, WS_FLOATS * sizeof(float), stream);

    dim3 gp(NCHUNK, N_IMG);   // 313 x 4 blocks
    k_sums<<<gp, 256, 0, stream>>>(emb, target, ws);
    k_means_dist<<<N_IMG, 256, 0, stream>>>(ws);
    k_var<<<gp, 256, 0, stream>>>(emb, target, ws);
    k_fin<<<1, 1, 0, stream>>>(ws, out);
}